// Round 3
// baseline (874.240 us; speedup 1.0000x reference)
//
#include <hip/hip_runtime.h>
#include <hip/hip_bf16.h>

typedef __bf16 bf16x8 __attribute__((ext_vector_type(8)));
typedef __bf16 bf16x4 __attribute__((ext_vector_type(4)));
typedef float  f32x4  __attribute__((ext_vector_type(4)));

#define N_IN 1024
#define BM   64
#define NTHR 640   // 8 consumer waves + 2 producer waves

// Convert B (fp32, 1024x1024) to bf16 in workspace.
__global__ void convB_kernel(const float* __restrict__ B, __bf16* __restrict__ Bb) {
    int i = blockIdx.x * blockDim.x + threadIdx.x;
    f32x4 v = ((const f32x4*)B)[i];
    bf16x4 o;
    o[0] = (__bf16)v[0]; o[1] = (__bf16)v[1]; o[2] = (__bf16)v[2]; o[3] = (__bf16)v[3];
    ((bf16x4*)Bb)[i] = o;
}

// Wave-specialized fused kernel:
//   waves 0-7 (consumers): Y = O @ B^T via MFMA (B-frags from L2 only -> clean vmcnt),
//   waves 8-9 (producers): stage o = num * avg^alpha into swizzled LDS panel (HBM only).
// Producer stages quarter q+1 while consumers compute quarter q (disjoint panel regions).
template<bool USEBF>
__global__ __launch_bounds__(NTHR, 2)
void fused_kernel(const float* __restrict__ x, const float* __restrict__ A,
                  const float* __restrict__ Bf, const __bf16* __restrict__ Bb,
                  const float* __restrict__ Cp, const float* __restrict__ alpha,
                  float* __restrict__ out) {
    __shared__ __align__(16) __bf16 o_panel[BM * N_IN];   // 128 KB, XOR-swizzled
    __shared__ float rowsum[8][BM];                       // 2 KB

    const int t    = threadIdx.x;
    const int wave = t >> 6;
    const int lane = t & 63;
    const int lrow = lane & 15;
    const int lgrp = lane >> 4;
    const long blk_row = (long)blockIdx.x * BM;
    const int  colbase = wave * 128;                      // consumer column base

    f32x4 acc[4][8];
    #pragma unroll
    for (int m = 0; m < 4; ++m)
        #pragma unroll
        for (int n = 0; n < 8; ++n)
            acc[m][n] = f32x4{0.f, 0.f, 0.f, 0.f};

    // 5 ticks: tick q -> producer stages quarter q (q<4), consumers compute quarter q-1 (q>=1)
    #pragma unroll 1
    for (int tick = 0; tick < 5; ++tick) {
        if (wave < 8) {
            if (tick >= 1) {
                const int qq = tick - 1;
                #pragma unroll
                for (int kq = 0; kq < 8; ++kq) {
                    const int kk = (qq * 8 + kq) * 32 + lgrp * 8;
                    // A-frags from swizzled LDS ((m*16+lrow)&7 == lrow&7)
                    const int asw = kk ^ ((lrow & 7) << 3);
                    bf16x8 afr[4];
                    #pragma unroll
                    for (int m = 0; m < 4; ++m)
                        afr[m] = *(const bf16x8*)&o_panel[(m * 16 + lrow) * N_IN + asw];
                    // B-frags direct from L2
                    bf16x8 bfr[8];
                    #pragma unroll
                    for (int n = 0; n < 8; ++n) {
                        const int i = colbase + n * 16 + lrow;
                        if constexpr (USEBF) {
                            bfr[n] = *(const bf16x8*)&Bb[(long)i * N_IN + kk];
                        } else {
                            const float* p = Bf + (long)i * N_IN + kk;
                            f32x4 lo = *(const f32x4*)p;
                            f32x4 hi = *(const f32x4*)(p + 4);
                            #pragma unroll
                            for (int e = 0; e < 4; ++e) {
                                bfr[n][e]     = (__bf16)lo[e];
                                bfr[n][e + 4] = (__bf16)hi[e];
                            }
                        }
                    }
                    #pragma unroll
                    for (int m = 0; m < 4; ++m)
                        #pragma unroll
                        for (int n = 0; n < 8; ++n)
                            acc[m][n] = __builtin_amdgcn_mfma_f32_16x16x32_bf16(
                                afr[m], bfr[n], acc[m][n], 0, 0, 0);
                }
            }
        } else {
            if (tick < 4) {
                const int pt   = t - 512;          // 0..127
                const int prow = pt >> 1;          // 0..63
                const int pko  = (pt & 1) * 16;    // 0 or 16
                const float* xr = x + (blk_row + prow) * (2 * N_IN);
                const int sw = (prow & 7) << 3;
                const int pbase = prow * N_IN;
                #pragma unroll 2
                for (int c = 0; c < 8; ++c) {
                    const int kb = (tick * 8 + c) * 32 + pko;   // 16 consecutive k
                    f32x4 va[4], vn[4], vl[4];
                    #pragma unroll
                    for (int u = 0; u < 4; ++u) {
                        va[u] = *(const f32x4*)(xr + kb + 4 * u);
                        vn[u] = *(const f32x4*)(xr + N_IN + kb + 4 * u);
                        vl[u] = *(const f32x4*)(alpha + kb + 4 * u);
                    }
                    bf16x8 w[2];
                    #pragma unroll
                    for (int u = 0; u < 4; ++u)
                        #pragma unroll
                        for (int e = 0; e < 4; ++e) {
                            float ov = vn[u][e] * __expf(vl[u][e] * __logf(va[u][e]));
                            w[u >> 1][(u & 1) * 4 + e] = (__bf16)ov;
                        }
                    *(bf16x8*)&o_panel[pbase + (kb ^ sw)]       = w[0];
                    *(bf16x8*)&o_panel[pbase + ((kb + 8) ^ sw)] = w[1];
                }
            }
        }
        __syncthreads();
    }

    // ---- epilogue: rowpart[r] = sum_i (Y[r][i] + A[i]) * o[r][i] ----
    if (wave < 8) {
        float rp[16];
        #pragma unroll
        for (int i = 0; i < 16; ++i) rp[i] = 0.f;
        #pragma unroll
        for (int n = 0; n < 8; ++n) {
            const int i = colbase + n * 16 + lrow;
            const float Ai = A[i];
            #pragma unroll
            for (int m = 0; m < 4; ++m)
                #pragma unroll
                for (int j = 0; j < 4; ++j) {
                    const int r = m * 16 + lgrp * 4 + j;   // C/D layout (m89-verified)
                    float ov = (float)o_panel[r * N_IN + ((i & ~7) ^ ((r & 7) << 3)) + (i & 7)];
                    rp[m * 4 + j] += (acc[m][n][j] + Ai) * ov;
                }
        }
        #pragma unroll
        for (int d = 1; d < 16; d <<= 1)
            #pragma unroll
            for (int i = 0; i < 16; ++i)
                rp[i] += __shfl_xor(rp[i], d);
        if (lrow == 0) {
            #pragma unroll
            for (int m = 0; m < 4; ++m)
                #pragma unroll
                for (int j = 0; j < 4; ++j)
                    rowsum[wave][m * 16 + lgrp * 4 + j] = rp[m * 4 + j];
        }
    }
    __syncthreads();
    if (t < BM) {
        float s = Cp[0];
        #pragma unroll
        for (int w = 0; w < 8; ++w) s += rowsum[w][t];
        out[blk_row + t] = s;
    }
}

extern "C" void kernel_launch(void* const* d_in, const int* in_sizes, int n_in,
                              void* d_out, int out_size, void* d_ws, size_t ws_size,
                              hipStream_t stream) {
    const float* x     = (const float*)d_in[0];
    const float* A     = (const float*)d_in[1];
    const float* B     = (const float*)d_in[2];
    const float* C     = (const float*)d_in[3];
    const float* alpha = (const float*)d_in[4];
    float* out = (float*)d_out;

    int batch = in_sizes[0] / (2 * N_IN);   // 65536
    int grid  = batch / BM;                 // 1024

    bool useBf = (ws_size >= (size_t)(N_IN * N_IN * sizeof(__bf16)));
    if (useBf) {
        __bf16* Bb = (__bf16*)d_ws;
        int nvec = (N_IN * N_IN) / 4;
        convB_kernel<<<nvec / 256, 256, 0, stream>>>(B, Bb);
        fused_kernel<true><<<grid, NTHR, 0, stream>>>(x, A, nullptr, Bb, C, alpha, out);
    } else {
        fused_kernel<false><<<grid, NTHR, 0, stream>>>(x, A, B, nullptr, C, alpha, out);
    }
}